// Round 4
// baseline (191.117 us; speedup 1.0000x reference)
//
#include <hip/hip_runtime.h>

#define NB 32
#define NL 1024
#define NC 64
#define NO 64
constexpr float BN_EPS = 1e-5f;

// ws layout (floats):
//  [0..63]      scale
//  [64..127]    shift
//  [128..32895] d  (B*L row degrees)
//  [32896..65663] bn partials (256 blocks x 64 ch, sum then sumsq)
//  [65664 ..)   Y = rsqrt(d) * X   (B*L*NO floats, 8 MB)
#define SCALE_OFF 0
#define SHIFT_OFF 64
#define D_OFF 128
#define PART_OFF 32896
#define Y_OFF 65664

// ---------------- Kernel 1: BN partial sums (per-channel sum, sumsq) ----------
__global__ void bn_stats(const float* __restrict__ H, float* __restrict__ ws) {
    int tid = threadIdx.x;
    int c = tid & 63, rg = tid >> 6;
    float s = 0.f, s2 = 0.f;
    for (int r = blockIdx.x * 4 + rg; r < NB * NL; r += 256 * 4) {
        float v = H[r * NC + c];
        s += v;
        s2 += v * v;
    }
    __shared__ float ls[256], ls2[256];
    ls[tid] = s; ls2[tid] = s2;
    __syncthreads();
    if (tid < 64) {
        float t  = ls[c]  + ls[c + 64]  + ls[c + 128]  + ls[c + 192];
        float t2 = ls2[c] + ls2[c + 64] + ls2[c + 128] + ls2[c + 192];
        ws[PART_OFF + blockIdx.x * 64 + c] = t;
        ws[PART_OFF + 256 * 64 + blockIdx.x * 64 + c] = t2;
    }
}

// ---------------- Kernel 2: finalize BN -> scale/shift ------------------------
__global__ void bn_finalize(const float* __restrict__ gamma,
                            const float* __restrict__ beta,
                            float* __restrict__ ws) {
    __shared__ float ls[256], ls2[256];
    int tid = threadIdx.x;
    int c = tid & 63, q = tid >> 6;
    const float* ps  = ws + PART_OFF;
    const float* ps2 = ws + PART_OFF + 256 * 64;
    float s = 0.f, s2 = 0.f;
    for (int p = q * 64; p < q * 64 + 64; ++p) {
        s  += ps[p * 64 + c];
        s2 += ps2[p * 64 + c];
    }
    ls[tid] = s; ls2[tid] = s2;
    __syncthreads();
    if (tid < 64) {
        float t  = ls[c]  + ls[c + 64]  + ls[c + 128]  + ls[c + 192];
        float t2 = ls2[c] + ls2[c + 64] + ls2[c + 128] + ls2[c + 192];
        const float n = (float)(NB * NL);
        float mean = t / n;
        float var  = t2 / n - mean * mean;
        float sc = gamma[c] * rsqrtf(var + BN_EPS);
        ws[SCALE_OFF + c] = sc;
        ws[SHIFT_OFF + c] = beta[c] - mean * sc;
    }
}

// ---------------- Kernel 3: row degrees d[b,i] = sum_j A[b,i,j] ---------------
__global__ void row_degree(const float* __restrict__ A, float* __restrict__ dbuf) {
    int w = threadIdx.x >> 6;
    int lane = threadIdx.x & 63;
    int row = blockIdx.x * 4 + w;            // 0..32767
    const float* ap = A + (size_t)row * NL;
    float s = 0.f;
#pragma unroll
    for (int k = 0; k < 4; ++k) {
        float4 v = *(const float4*)(ap + k * 256 + lane * 4);
        s += v.x + v.y + v.z + v.w;
    }
#pragma unroll
    for (int off = 32; off; off >>= 1) s += __shfl_down(s, off, 64);
    if (lane == 0) dbuf[row] = s;
}

// ---------------- Kernel 4: X = Hn@W + b -> d_out;  Y = rsqrt(d)*X -> ws ------
__global__ void linear_xy(const float* __restrict__ H, const float* __restrict__ Wm,
                          const float* __restrict__ bias, const float* __restrict__ ws,
                          float* __restrict__ X, float* __restrict__ Y) {
    __shared__ float Wl[NC * NO];     // 16 KB
    __shared__ float hn[4][NC];
    int tid = threadIdx.x, lane = tid & 63, w = tid >> 6;
    for (int k = tid; k < NC * NO; k += 256) Wl[k] = Wm[k];
    float sc = ws[SCALE_OFF + lane];
    float sh = ws[SHIFT_OFF + lane];
    float bo = bias[lane];
    __syncthreads();
    const float* dbuf = ws + D_OFF;
    for (int row = blockIdx.x * 4 + w; row < NB * NL; row += 2048 * 4) {
        float h = H[row * NC + lane];
        hn[w][lane] = h * sc + sh;               // lane = channel here
        float x = bo;                            // lane = output col below
#pragma unroll
        for (int c4 = 0; c4 < NC; c4 += 4) {
            float4 h4 = *(const float4*)(&hn[w][c4]);   // wave-uniform broadcast
            x += h4.x * Wl[(c4 + 0) * NO + lane];
            x += h4.y * Wl[(c4 + 1) * NO + lane];
            x += h4.z * Wl[(c4 + 2) * NO + lane];
            x += h4.w * Wl[(c4 + 3) * NO + lane];
        }
        X[row * NO + lane] = x;
        Y[row * NO + lane] = x * rsqrtf(dbuf[row]);
    }
}

// ---------------- Kernel 5: out = leaky(X - sqrt(d_i) * A @ Y) ----------------
#define BM 64
#define KT 64
__global__ __launch_bounds__(256) void prop(const float* __restrict__ A,
                                            const float* __restrict__ Yg,
                                            const float* __restrict__ dbuf,
                                            float* __restrict__ XO) {
    __shared__ float Al[BM * KT];     // 16 KB
    __shared__ float Yl[KT * NO];     // 16 KB
    int bid = blockIdx.x;
    int b = bid >> 4;                  // 16 row-tiles per batch
    int mt = bid & 15;
    int i0 = mt * BM;
    const float* Ab = A + ((size_t)b * NL + i0) * NL;
    const float* Yb = Yg + (size_t)b * NL * NO;
    int tid = threadIdx.x;
    int lane = tid & 63;
    int w = tid >> 6;
    int seg = tid & 15, rowb = tid >> 4;

    float acc[16];
#pragma unroll
    for (int r = 0; r < 16; ++r) acc[r] = 0.f;

    for (int kt = 0; kt < NL; kt += KT) {
        // stage A tile [BM][KT]
#pragma unroll
        for (int p = 0; p < 4; ++p) {
            int row = rowb + p * 16;
            float4 v = *(const float4*)(Ab + (size_t)row * NL + kt + seg * 4);
            *(float4*)(&Al[row * KT + seg * 4]) = v;
        }
        // stage Y tile [KT][NO]
#pragma unroll
        for (int p = 0; p < 4; ++p) {
            int jj = rowb + p * 16;
            float4 v = *(const float4*)(Yb + (size_t)(kt + jj) * NO + seg * 4);
            *(float4*)(&Yl[jj * NO + seg * 4]) = v;
        }
        __syncthreads();
#pragma unroll 4
        for (int j = 0; j < KT; j += 4) {
            float y0 = Yl[(j + 0) * NO + lane];
            float y1 = Yl[(j + 1) * NO + lane];
            float y2 = Yl[(j + 2) * NO + lane];
            float y3 = Yl[(j + 3) * NO + lane];
#pragma unroll
            for (int r = 0; r < 16; ++r) {
                float4 a4 = *(const float4*)(&Al[(w * 16 + r) * KT + j]);  // broadcast
                acc[r] += a4.x * y0;
                acc[r] += a4.y * y1;
                acc[r] += a4.z * y2;
                acc[r] += a4.w * y3;
            }
        }
        __syncthreads();
    }
    // epilogue: out = leaky(X - sqrt(d_i)*acc)
#pragma unroll
    for (int r = 0; r < 16; ++r) {
        int i = i0 + w * 16 + r;
        float sd = sqrtf(dbuf[b * NL + i]);
        size_t idx = ((size_t)b * NL + i) * NO + lane;
        float x = XO[idx];
        float v = x - sd * acc[r];
        XO[idx] = v > 0.f ? v : 0.01f * v;
    }
}

extern "C" void kernel_launch(void* const* d_in, const int* in_sizes, int n_in,
                              void* d_out, int out_size, void* d_ws, size_t ws_size,
                              hipStream_t stream) {
    const float* H     = (const float*)d_in[0];
    const float* A     = (const float*)d_in[1];
    const float* gamma = (const float*)d_in[2];
    const float* beta  = (const float*)d_in[3];
    const float* Wm    = (const float*)d_in[4];
    const float* bias  = (const float*)d_in[5];
    float* out = (float*)d_out;
    float* ws  = (float*)d_ws;
    float* Y   = ws + Y_OFF;

    bn_stats<<<256, 256, 0, stream>>>(H, ws);
    bn_finalize<<<1, 256, 0, stream>>>(gamma, beta, ws);
    row_degree<<<8192, 256, 0, stream>>>(A, ws + D_OFF);
    linear_xy<<<2048, 256, 0, stream>>>(H, Wm, bias, ws, out, Y);
    prop<<<512, 256, 0, stream>>>(A, Y, ws + D_OFF, out);
}

// Round 5
// 94.420 us; speedup vs baseline: 2.0241x; 2.0241x over previous
//
#include <hip/hip_runtime.h>

#define NB 32
#define NL 1024
#define NC 64
#define NO 64
constexpr float BN_EPS = 1e-5f;

// ws layout (floats):
//  [0..63]       scale
//  [64..127]     shift
//  [128..32895]  d  (B*L row degrees)
//  [32896..65663] bn partials (256 blocks x 64 ch, sum then sumsq)
//  [65664 ..)    Yt = transposed bf16 Y, [B][NO][NL] ushorts (4 MB)
#define SCALE_OFF 0
#define SHIFT_OFF 64
#define D_OFF 128
#define PART_OFF 32896
#define YT_OFF 65664

typedef short          s16x8 __attribute__((ext_vector_type(8)));
typedef unsigned short u16x8 __attribute__((ext_vector_type(8)));
typedef unsigned short u16x4 __attribute__((ext_vector_type(4)));
typedef float          f32x16 __attribute__((ext_vector_type(16)));

__device__ inline unsigned short f2bf(float f) {
    union { float f; unsigned u; } v; v.f = f;
    unsigned u = v.u + 0x7FFFu + ((v.u >> 16) & 1u);   // round-to-nearest-even
    return (unsigned short)(u >> 16);
}

// ---------------- Kernel 1: BN partial sums (per-channel sum, sumsq) ----------
__global__ void bn_stats(const float* __restrict__ H, float* __restrict__ ws) {
    int tid = threadIdx.x;
    int c = tid & 63, rg = tid >> 6;
    float s = 0.f, s2 = 0.f;
    for (int r = blockIdx.x * 4 + rg; r < NB * NL; r += 256 * 4) {
        float v = H[r * NC + c];
        s += v;
        s2 += v * v;
    }
    __shared__ float ls[256], ls2[256];
    ls[tid] = s; ls2[tid] = s2;
    __syncthreads();
    if (tid < 64) {
        float t  = ls[c]  + ls[c + 64]  + ls[c + 128]  + ls[c + 192];
        float t2 = ls2[c] + ls2[c + 64] + ls2[c + 128] + ls2[c + 192];
        ws[PART_OFF + blockIdx.x * 64 + c] = t;
        ws[PART_OFF + 256 * 64 + blockIdx.x * 64 + c] = t2;
    }
}

// ---------------- Kernel 2: finalize BN -> scale/shift ------------------------
__global__ void bn_finalize(const float* __restrict__ gamma,
                            const float* __restrict__ beta,
                            float* __restrict__ ws) {
    __shared__ float ls[256], ls2[256];
    int tid = threadIdx.x;
    int c = tid & 63, q = tid >> 6;
    const float* ps  = ws + PART_OFF;
    const float* ps2 = ws + PART_OFF + 256 * 64;
    float s = 0.f, s2 = 0.f;
    for (int p = q * 64; p < q * 64 + 64; ++p) {
        s  += ps[p * 64 + c];
        s2 += ps2[p * 64 + c];
    }
    ls[tid] = s; ls2[tid] = s2;
    __syncthreads();
    if (tid < 64) {
        float t  = ls[c]  + ls[c + 64]  + ls[c + 128]  + ls[c + 192];
        float t2 = ls2[c] + ls2[c + 64] + ls2[c + 128] + ls2[c + 192];
        const float n = (float)(NB * NL);
        float mean = t / n;
        float var  = t2 / n - mean * mean;
        float sc = gamma[c] * rsqrtf(var + BN_EPS);
        ws[SCALE_OFF + c] = sc;
        ws[SHIFT_OFF + c] = beta[c] - mean * sc;
    }
}

// ---------------- Kernel 3: row degrees d[b,i] = sum_j A[b,i,j] ---------------
__global__ void row_degree(const float* __restrict__ A, float* __restrict__ dbuf) {
    int w = threadIdx.x >> 6;
    int lane = threadIdx.x & 63;
    int row = blockIdx.x * 4 + w;            // 0..32767
    const float* ap = A + (size_t)row * NL;
    float s = 0.f;
#pragma unroll
    for (int k = 0; k < 4; ++k) {
        float4 v = *(const float4*)(ap + k * 256 + lane * 4);
        s += v.x + v.y + v.z + v.w;
    }
#pragma unroll
    for (int off = 32; off; off >>= 1) s += __shfl_down(s, off, 64);
    if (lane == 0) dbuf[row] = s;
}

// ---- Kernel 4: X = Hn@W + b -> d_out;  Yt[b][col][k] = bf16(rsqrt(d)*X) ------
__global__ __launch_bounds__(256) void linear_xy(
    const float* __restrict__ H, const float* __restrict__ Wm,
    const float* __restrict__ bias, const float* __restrict__ ws,
    float* __restrict__ X, unsigned short* __restrict__ Yt) {
    __shared__ float Wl[NC * NO];            // 16 KB
    __shared__ float hnbuf[4][NC];
    __shared__ unsigned short ytile[64][66]; // pad 2 -> 2-way (free) on transpose read
    const int b = blockIdx.x >> 4, ch = blockIdx.x & 15;
    const int r0g = b * NL + ch * 64;        // first global node row of this block
    const int t = threadIdx.x, lane = t & 63, w = t >> 6;
    for (int k = t; k < NC * NO; k += 256) Wl[k] = Wm[k];
    const float sc = ws[SCALE_OFF + lane];
    const float sh = ws[SHIFT_OFF + lane];
    const float bo = bias[lane];
    const float* dbuf = ws + D_OFF;
    __syncthreads();
    for (int rr = w; rr < 64; rr += 4) {
        const int row = r0g + rr;
        float h = H[(size_t)row * NC + lane];
        hnbuf[w][lane] = h * sc + sh;        // lane = channel
        float x = bo;                        // lane = output col
#pragma unroll
        for (int c4 = 0; c4 < NC; c4 += 4) {
            float4 h4 = *(const float4*)(&hnbuf[w][c4]);  // wave-uniform broadcast
            x += h4.x * Wl[(c4 + 0) * NO + lane];
            x += h4.y * Wl[(c4 + 1) * NO + lane];
            x += h4.z * Wl[(c4 + 2) * NO + lane];
            x += h4.w * Wl[(c4 + 3) * NO + lane];
        }
        X[(size_t)row * NO + lane] = x;
        ytile[rr][lane] = f2bf(x * rsqrtf(dbuf[row]));
    }
    __syncthreads();
    // transposed, coalesced write: Yt[b][col][r0..r0+63]
#pragma unroll
    for (int i2 = 0; i2 < 16; ++i2) {
        const int col = i2 * 4 + w;
        Yt[((size_t)b * NO + col) * NL + ch * 64 + lane] = ytile[lane][col];
    }
}

// ---------------- Kernel 5: out = leaky(X - sqrt(d_i) * (A @ Y))  [MFMA] ------
// Per block: 128 rows x 64 cols of one batch. 8 waves, each one 32x32 fragment.
// A staged fp32->bf16 to LDS, Yt staged bf16; both XOR-swizzled ((row&7)<<4)
// so fragment ds_read_b128 across 32 lanes is throughput-optimal.
__global__ __launch_bounds__(512) void prop_mfma(
    const float* __restrict__ A, const unsigned short* __restrict__ Yt,
    const float* __restrict__ dbuf, float* __restrict__ XO) {

    __shared__ unsigned short Abuf[2][128 * 64];   // 2 x 16 KB
    __shared__ unsigned short Ybuf[2][64 * 64];    // 2 x 8 KB  ([col][k])
    __shared__ float sdl[128];

    const int b  = blockIdx.x >> 3;
    const int mt = blockIdx.x & 7;
    const int i0 = mt * 128;
    const float* Ab = A + ((size_t)(b * NL + i0)) * NL;
    const unsigned short* Yb = Yt + (size_t)b * (NO * NL);

    const int t    = threadIdx.x;
    const int lane = t & 63;
    const int w    = t >> 6;

    if (t < 128) sdl[t] = sqrtf(dbuf[b * NL + i0 + t]);

    // staging mapping: A: 4 rounds, 16 lanes cover one row's 64 floats (256B coalesced)
    const int arow = t >> 4;          // 0..31 (+32 per round)
    const int akk  = (t & 15) * 4;    // float4 start within K-tile
    const int ycol = t >> 3;          // 0..63
    const int yke  = (t & 7) * 8;     // ushort8 start within K-tile

    // wave fragment position
    const int wr0  = (w >> 1) * 32;
    const int wc0  = (w & 1) * 32;
    const int frow = wr0 + (lane & 31);
    const int fcol = wc0 + (lane & 31);
    const int khb  = (lane >> 5) * 16;    // byte offset of this half's 8 bf16

    float4 areg[4];
    u16x8  yreg;

    f32x16 acc;
#pragma unroll
    for (int r = 0; r < 16; ++r) acc[r] = 0.f;

    // ---- prologue: tile 0 ----
#pragma unroll
    for (int r = 0; r < 4; ++r)
        areg[r] = *(const float4*)(Ab + (size_t)(r * 32 + arow) * NL + akk);
    yreg = *(const u16x8*)(Yb + (size_t)ycol * NL + yke);
    {
        char* ab = (char*)Abuf[0];
#pragma unroll
        for (int r = 0; r < 4; ++r) {
            int row = r * 32 + arow;
            u16x4 h;
            h[0] = f2bf(areg[r].x); h[1] = f2bf(areg[r].y);
            h[2] = f2bf(areg[r].z); h[3] = f2bf(areg[r].w);
            *(u16x4*)(ab + ((row * 128 + akk * 2) ^ ((row & 7) << 4))) = h;
        }
        char* yb2 = (char*)Ybuf[0];
        *(u16x8*)(yb2 + ((ycol * 128 + yke * 2) ^ ((ycol & 7) << 4))) = yreg;
    }
    __syncthreads();

#pragma unroll 1
    for (int kti = 0; kti < 16; ++kti) {
        const int nxt = kti + 1;
        if (nxt < 16) {                     // issue next tile's global loads EARLY
            const int kt = nxt * 64;
#pragma unroll
            for (int r = 0; r < 4; ++r)
                areg[r] = *(const float4*)(Ab + (size_t)(r * 32 + arow) * NL + kt + akk);
            yreg = *(const u16x8*)(Yb + (size_t)ycol * NL + kt + yke);
        }
        {   // compute on buffer kti&1
            const char* ab  = (const char*)Abuf[kti & 1];
            const char* yb2 = (const char*)Ybuf[kti & 1];
#pragma unroll
            for (int ks = 0; ks < 4; ++ks) {
                const int kb = ks * 32 + khb;
                s16x8 af = *(const s16x8*)(ab  + ((frow * 128 + kb) ^ ((frow & 7) << 4)));
                s16x8 bf = *(const s16x8*)(yb2 + ((fcol * 128 + kb) ^ ((fcol & 7) << 4)));
                acc = __builtin_amdgcn_mfma_f32_32x32x16_bf16(af, bf, acc, 0, 0, 0);
            }
        }
        if (nxt < 16) {                     // convert + write late (vmcnt by compiler)
            char* ab = (char*)Abuf[nxt & 1];
#pragma unroll
            for (int r = 0; r < 4; ++r) {
                int row = r * 32 + arow;
                u16x4 h;
                h[0] = f2bf(areg[r].x); h[1] = f2bf(areg[r].y);
                h[2] = f2bf(areg[r].z); h[3] = f2bf(areg[r].w);
                *(u16x4*)(ab + ((row * 128 + akk * 2) ^ ((row & 7) << 4))) = h;
            }
            char* yb2 = (char*)Ybuf[nxt & 1];
            *(u16x8*)(yb2 + ((ycol * 128 + yke * 2) ^ ((ycol & 7) << 4))) = yreg;
        }
        __syncthreads();
    }

    // ---- epilogue: out = leaky(X - sqrt(d_i) * acc) ----
#pragma unroll
    for (int reg = 0; reg < 16; ++reg) {
        int row = (reg & 3) + 8 * (reg >> 2) + 4 * (lane >> 5);
        int i   = i0 + wr0 + row;
        int col = wc0 + (lane & 31);
        size_t idx = ((size_t)(b * NL + i)) * NO + col;
        float x = XO[idx];
        float v = x - sdl[wr0 + row] * acc[reg];
        XO[idx] = v > 0.f ? v : 0.01f * v;
    }
}

extern "C" void kernel_launch(void* const* d_in, const int* in_sizes, int n_in,
                              void* d_out, int out_size, void* d_ws, size_t ws_size,
                              hipStream_t stream) {
    const float* H     = (const float*)d_in[0];
    const float* A     = (const float*)d_in[1];
    const float* gamma = (const float*)d_in[2];
    const float* beta  = (const float*)d_in[3];
    const float* Wm    = (const float*)d_in[4];
    const float* bias  = (const float*)d_in[5];
    float* out = (float*)d_out;
    float* ws  = (float*)d_ws;
    unsigned short* Yt = (unsigned short*)(ws + YT_OFF);

    bn_stats<<<256, 256, 0, stream>>>(H, ws);
    bn_finalize<<<1, 256, 0, stream>>>(gamma, beta, ws);
    row_degree<<<8192, 256, 0, stream>>>(A, ws + D_OFF);
    linear_xy<<<512, 256, 0, stream>>>(H, Wm, bias, ws, out, Yt);
    prop_mfma<<<256, 512, 0, stream>>>(A, Yt, ws + D_OFF, out);
}

// Round 6
// 81.337 us; speedup vs baseline: 2.3497x; 1.1608x over previous
//
#include <hip/hip_runtime.h>

#define NB 32
#define NL 1024
#define NC 64
#define NO 64
constexpr float BN_EPS = 1e-5f;

// ws layout (float units):
//  [0..63]        scale
//  [64..127]      shift
//  [128..32895]   d  (B*L row degrees)
//  [32896..49279] bn partials (128 blocks x 64 ch, sum then sumsq)
//  [131072..]     Yt tiled bf16: [b][kt] 8KB tiles, swizzled   (4 MB)
//  [2097152..]    Abf tiled bf16: [b][mt][kt] 16KB tiles, swizzled (64 MB)
#define SCALE_OFF 0
#define SHIFT_OFF 64
#define D_OFF 128
#define PART_OFF 32896
#define YT_OFF 131072      // byte 512 KB (8KB aligned)
#define ABF_OFF 2097152    // byte 8 MB  (16KB aligned)

typedef short          s16x8 __attribute__((ext_vector_type(8)));
typedef unsigned short u16x4 __attribute__((ext_vector_type(4)));
typedef float          f32x16 __attribute__((ext_vector_type(16)));

__device__ inline unsigned short f2bf(float f) {
    union { float f; unsigned u; } v; v.f = f;
    unsigned u = v.u + 0x7FFFu + ((v.u >> 16) & 1u);   // round-to-nearest-even
    return (unsigned short)(u >> 16);
}

__device__ inline void gload16(const void* g, void* l) {
    __builtin_amdgcn_global_load_lds(
        (const __attribute__((address_space(1))) unsigned int*)g,
        (__attribute__((address_space(3))) unsigned int*)l, 16, 0, 0);
}

// ---- Kernel 1: fused  (blocks 0..255: A degrees + bf16 tile convert)
//                (blocks 256..383: BN partial sums over H) ---------------------
__global__ __launch_bounds__(512) void degcvt_bn(
    const float* __restrict__ A, const float* __restrict__ H,
    float* __restrict__ ws, unsigned short* __restrict__ Abf) {
    const int t = threadIdx.x;
    if (blockIdx.x < 256) {
        const int b = blockIdx.x >> 3, mt = blockIdx.x & 7;
        const int f4 = t & 15;            // float4 index within a row's K-tile
        const int rb = t >> 4;            // 0..31
        const float* Ab = A + ((size_t)(b * NL + mt * 128)) * NL;
        char* tbase = (char*)(Abf) + (size_t)blockIdx.x * 16 * 16384;
        float dsum0 = 0.f, dsum1 = 0.f, dsum2 = 0.f, dsum3 = 0.f;
        for (int kt = 0; kt < 16; ++kt) {
            char* tb = tbase + kt * 16384;
#pragma unroll
            for (int rg = 0; rg < 4; ++rg) {
                const int r = rg * 32 + rb;
                float4 v = *(const float4*)(Ab + (size_t)r * NL + kt * 64 + f4 * 4);
                u16x4 h;
                h[0] = f2bf(v.x); h[1] = f2bf(v.y); h[2] = f2bf(v.z); h[3] = f2bf(v.w);
                *(u16x4*)(tb + ((r * 128 + f4 * 8) ^ ((r & 7) << 4))) = h;
                float s = v.x + v.y + v.z + v.w;
                if (rg == 0) dsum0 += s; else if (rg == 1) dsum1 += s;
                else if (rg == 2) dsum2 += s; else dsum3 += s;
            }
        }
        // reduce across the 16 lanes sharing a row
#pragma unroll
        for (int m = 8; m; m >>= 1) {
            dsum0 += __shfl_xor(dsum0, m, 64);
            dsum1 += __shfl_xor(dsum1, m, 64);
            dsum2 += __shfl_xor(dsum2, m, 64);
            dsum3 += __shfl_xor(dsum3, m, 64);
        }
        if (f4 == 0) {
            float* dp = ws + D_OFF + b * NL + mt * 128 + rb;
            dp[0]  = dsum0; dp[32] = dsum1; dp[64] = dsum2; dp[96] = dsum3;
        }
    } else {
        __shared__ float ls[512], ls2[512];
        const int bb = blockIdx.x - 256;       // 0..127
        const int c = t & 63, rg = t >> 6;     // rg 0..7
        float s = 0.f, s2 = 0.f;
        for (int r = bb * 8 + rg; r < NB * NL; r += 1024) {
            float v = H[(size_t)r * NC + c];
            s += v; s2 += v * v;
        }
        ls[t] = s; ls2[t] = s2;
        __syncthreads();
        if (t < 64) {
            float a = 0.f, a2 = 0.f;
#pragma unroll
            for (int j = 0; j < 8; ++j) { a += ls[c + 64 * j]; a2 += ls2[c + 64 * j]; }
            ws[PART_OFF + bb * 64 + c] = a;
            ws[PART_OFF + 128 * 64 + bb * 64 + c] = a2;
        }
    }
}

// ---- Kernel 2: finalize BN -> scale/shift ------------------------------------
__global__ void bn_finalize(const float* __restrict__ gamma,
                            const float* __restrict__ beta,
                            float* __restrict__ ws) {
    __shared__ float ls[256], ls2[256];
    int tid = threadIdx.x;
    int c = tid & 63, q = tid >> 6;
    const float* ps  = ws + PART_OFF;
    const float* ps2 = ws + PART_OFF + 128 * 64;
    float s = 0.f, s2 = 0.f;
    for (int p = q * 32; p < q * 32 + 32; ++p) {
        s  += ps[p * 64 + c];
        s2 += ps2[p * 64 + c];
    }
    ls[tid] = s; ls2[tid] = s2;
    __syncthreads();
    if (tid < 64) {
        float t  = ls[c]  + ls[c + 64]  + ls[c + 128]  + ls[c + 192];
        float t2 = ls2[c] + ls2[c + 64] + ls2[c + 128] + ls2[c + 192];
        const float n = (float)(NB * NL);
        float mean = t / n;
        float var  = t2 / n - mean * mean;
        float sc = gamma[c] * rsqrtf(var + BN_EPS);
        ws[SCALE_OFF + c] = sc;
        ws[SHIFT_OFF + c] = beta[c] - mean * sc;
    }
}

// ---- Kernel 3: X = Hn@W + b -> d_out;  Yt tiles = bf16(rsqrt(d)*X) swizzled --
__global__ __launch_bounds__(256) void linear_xy(
    const float* __restrict__ H, const float* __restrict__ Wm,
    const float* __restrict__ bias, const float* __restrict__ ws,
    float* __restrict__ X, unsigned short* __restrict__ Yt) {
    __shared__ float Wl[NC * NO];
    __shared__ float hnbuf[4][NC];
    __shared__ unsigned short ytile[64][66];
    const int b = blockIdx.x >> 4, ch = blockIdx.x & 15;   // ch = K-tile index
    const int r0g = b * NL + ch * 64;
    const int t = threadIdx.x, lane = t & 63, w = t >> 6;
    for (int k = t; k < NC * NO; k += 256) Wl[k] = Wm[k];
    const float sc = ws[SCALE_OFF + lane];
    const float sh = ws[SHIFT_OFF + lane];
    const float bo = bias[lane];
    const float* dbuf = ws + D_OFF;
    __syncthreads();
    for (int rr = w; rr < 64; rr += 4) {
        const int row = r0g + rr;
        float h = H[(size_t)row * NC + lane];
        hnbuf[w][lane] = h * sc + sh;
        float x = bo;
#pragma unroll
        for (int c4 = 0; c4 < NC; c4 += 4) {
            float4 h4 = *(const float4*)(&hnbuf[w][c4]);
            x += h4.x * Wl[(c4 + 0) * NO + lane];
            x += h4.y * Wl[(c4 + 1) * NO + lane];
            x += h4.z * Wl[(c4 + 2) * NO + lane];
            x += h4.w * Wl[(c4 + 3) * NO + lane];
        }
        X[(size_t)row * NO + lane] = x;
        ytile[rr][lane] = f2bf(x * rsqrtf(dbuf[row]));
    }
    __syncthreads();
    // tiled swizzled write: tile (b,ch), element (col, kk=lane)
    char* ybase = (char*)Yt + (size_t)(b * 16 + ch) * 8192;
#pragma unroll
    for (int i2 = 0; i2 < 16; ++i2) {
        const int col = i2 * 4 + w;
        *(unsigned short*)(ybase + ((col * 128 + lane * 2) ^ ((col & 7) << 4))) =
            ytile[lane][col];
    }
}

// ---- Kernel 4: out = leaky(X - sqrt(d_i) * (A @ Y))  [MFMA, gload_lds] -------
__global__ __launch_bounds__(512) void prop_mfma(
    const unsigned short* __restrict__ Abf, const unsigned short* __restrict__ Yt,
    const float* __restrict__ dbuf, float* __restrict__ XO) {

    __shared__ unsigned short Abuf[2][128 * 64];   // 2 x 16 KB (swizzled layout)
    __shared__ unsigned short Ybuf[2][64 * 64];    // 2 x 8 KB
    __shared__ float sdl[128];

    const int b  = blockIdx.x >> 3;
    const int mt = blockIdx.x & 7;
    const int i0 = mt * 128;
    const char* AbT = (const char*)Abf + (size_t)blockIdx.x * 16 * 16384;
    const char* YbT = (const char*)Yt  + (size_t)b * 16 * 8192;

    const int t    = threadIdx.x;
    const int lane = t & 63;
    const int w    = t >> 6;

    if (t < 128) sdl[t] = sqrtf(dbuf[b * NL + i0 + t]);

    const int wr0  = (w >> 1) * 32;
    const int wc0  = (w & 1) * 32;
    const int frow = wr0 + (lane & 31);
    const int fcol = wc0 + (lane & 31);
    const int khb  = (lane >> 5) * 16;

    f32x16 acc;
#pragma unroll
    for (int r = 0; r < 16; ++r) acc[r] = 0.f;

#define STAGE(bi, kt) do {                                                     \
        const char* asrc = AbT + (size_t)(kt) * 16384;                         \
        char* adst = (char*)Abuf[bi];                                          \
        gload16(asrc + w * 2048 + lane * 16,        adst + w * 2048 + lane * 16); \
        gload16(asrc + w * 2048 + 1024 + lane * 16, adst + w * 2048 + 1024 + lane * 16); \
        const char* ysrc = YbT + (size_t)(kt) * 8192;                          \
        gload16(ysrc + w * 1024 + lane * 16, (char*)Ybuf[bi] + w * 1024 + lane * 16); \
    } while (0)

    STAGE(0, 0);
    __syncthreads();

#pragma unroll 1
    for (int kti = 0; kti < 16; ++kti) {
        const int nxt = kti + 1;
        if (nxt < 16) STAGE(nxt & 1, nxt);      // prefetch next tile (async)
        const char* ab  = (const char*)Abuf[kti & 1];
        const char* yb2 = (const char*)Ybuf[kti & 1];
#pragma unroll
        for (int ks = 0; ks < 4; ++ks) {
            const int kb = ks * 32 + khb;
            s16x8 af = *(const s16x8*)(ab  + ((frow * 128 + kb) ^ ((frow & 7) << 4)));
            s16x8 bf = *(const s16x8*)(yb2 + ((fcol * 128 + kb) ^ ((fcol & 7) << 4)));
            acc = __builtin_amdgcn_mfma_f32_32x32x16_bf16(af, bf, acc, 0, 0, 0);
        }
        __syncthreads();                        // drains vmcnt: next tile resident
    }
#undef STAGE

    // epilogue: out = leaky(X - sqrt(d_i) * acc)
#pragma unroll
    for (int reg = 0; reg < 16; ++reg) {
        int row = (reg & 3) + 8 * (reg >> 2) + 4 * (lane >> 5);
        int i   = i0 + wr0 + row;
        int col = wc0 + (lane & 31);
        size_t idx = ((size_t)(b * NL + i)) * NO + col;
        float x = XO[idx];
        float v = x - sdl[wr0 + row] * acc[reg];
        XO[idx] = v > 0.f ? v : 0.01f * v;
    }
}

extern "C" void kernel_launch(void* const* d_in, const int* in_sizes, int n_in,
                              void* d_out, int out_size, void* d_ws, size_t ws_size,
                              hipStream_t stream) {
    const float* H     = (const float*)d_in[0];
    const float* A     = (const float*)d_in[1];
    const float* gamma = (const float*)d_in[2];
    const float* beta  = (const float*)d_in[3];
    const float* Wm    = (const float*)d_in[4];
    const float* bias  = (const float*)d_in[5];
    float* out = (float*)d_out;
    float* ws  = (float*)d_ws;
    unsigned short* Yt  = (unsigned short*)(ws + YT_OFF);
    unsigned short* Abf = (unsigned short*)(ws + ABF_OFF);

    degcvt_bn<<<384, 512, 0, stream>>>(A, H, ws, Abf);
    bn_finalize<<<1, 256, 0, stream>>>(gamma, beta, ws);
    linear_xy<<<512, 256, 0, stream>>>(H, Wm, bias, ws, out, Yt);
    prop_mfma<<<256, 512, 0, stream>>>(Abf, Yt, ws + D_OFF, out);
}